// Round 18
// baseline (183.769 us; speedup 1.0000x reference)
//
#include <hip/hip_runtime.h>
#include <cstdint>
#include <cstddef>

typedef _Float16 f16;
typedef f16 f16x8 __attribute__((ext_vector_type(8)));
typedef __fp16 fp16x2 __attribute__((ext_vector_type(2)));
typedef float f32x4 __attribute__((ext_vector_type(4)));
typedef float f32x16 __attribute__((ext_vector_type(16)));
typedef uint32_t u32;

// ---------------- helpers ----------------

__device__ __forceinline__ void gload16(const void* g, void* l) {
  __builtin_amdgcn_global_load_lds((const __attribute__((address_space(1))) void*)g,
                                   (__attribute__((address_space(3))) void*)l,
                                   16u, 0, 0u);
}

__device__ __forceinline__ u32 pkrtz(float a, float b) {
  union { fp16x2 v; u32 u; } t;
  t.v = __builtin_amdgcn_cvt_pkrtz(a, b);
  return t.u;
}

__device__ __forceinline__ u32 packh2(float a, float b) { return pkrtz(a, b); }

__device__ __forceinline__ float max3f(float a, float b, float c) {
  return fmaxf(fmaxf(a, b), c);
}

// exchange halves between a and b (used ONLY with distance>=8 from writes of
// its inputs -- VALU->permlane hazard; see R7 post-mortem)
__device__ __forceinline__ void pl32swap(u32& a, u32& b) {
  asm volatile("v_permlane32_swap_b32 %0, %1" : "+v"(a), "+v"(b));
}

// ---------------- fp32 -> fp16 convert ----------------

__global__ __launch_bounds__(256) void cvt_f32_f16(const float* __restrict__ in,
                                                   f16* __restrict__ out, int n) {
  int i = (blockIdx.x * 256 + threadIdx.x) * 8;
  if (i >= n) return;
  float4 a = *(const float4*)(in + i);
  float4 b = *(const float4*)(in + i + 4);
  f16x8 o;
  o[0] = (f16)a.x; o[1] = (f16)a.y; o[2] = (f16)a.z; o[3] = (f16)a.w;
  o[4] = (f16)b.x; o[5] = (f16)b.y; o[6] = (f16)b.z; o[7] = (f16)b.w;
  *(f16x8*)(out + i) = o;
}

// ---------------- bias factor tables ----------------

__global__ __launch_bounds__(256) void build_tables(const float* __restrict__ alpha,
                                                    const float* __restrict__ beta,
                                                    f16* __restrict__ U,
                                                    f16* __restrict__ Wt) {
  int idx = blockIdx.x * 256 + threadIdx.x;   // t*32 + r
  int t = idx >> 5, r = idx & 31;
  float w = powf(10000.0f, -(float)r / 32.0f);
  float ang = w * (float)t;
  float c = cosf(ang), s = sinf(ang);
  const float L2E = 1.44269504089f;
  U[t * 64 + 2 * r]     = (f16)(c * L2E);
  U[t * 64 + 2 * r + 1] = (f16)(s * L2E);
  #pragma unroll
  for (int h = 0; h < 16; ++h) {
    float al = alpha[h * 32 + r], be = beta[h * 32 + r];
    Wt[(size_t)(h * 2048 + t) * 64 + 2 * r]     = (f16)(al * c - be * s);
    Wt[(size_t)(h * 2048 + t) * 64 + 2 * r + 1] = (f16)(al * s + be * c);
  }
}

// ---------------- GEMM core (BM=256, BN=128, BK=64, 8 waves) ----------
// m-major-per-XCD partition (R14, proven).

__global__ __launch_bounds__(512, 2) void gemm_qkv(const f16* __restrict__ A,
                                                   const f16* __restrict__ B,
                                                   f16* __restrict__ Q,
                                                   f16* __restrict__ Kh,
                                                   f16* __restrict__ Vt) {
  __shared__ __align__(16) char sm[147456];
  const int K = 1024;
  int tid = threadIdx.x;
  int lane = tid & 63, wid = tid >> 6;
  int bid = blockIdx.x;
  int xcd = bid & 7;
  int id = bid >> 3;
  int ml = id / 24;
  int nn = id % 24;
  int m0 = (xcd * 4 + ml) * 256;
  int n0 = nn * 128;
  int wm = wid >> 1, wn = wid & 1;
  int c = lane & 15, g = lane >> 4;
  int swz = (c & 7) << 4;

  const f16* asrc[4]; int adst[4];
  #pragma unroll
  for (int i = 0; i < 4; ++i) {
    int p = i * 8192 + tid * 16;
    int row = p >> 7;
    int col = (p & 127) ^ ((row & 7) << 4);
    asrc[i] = A + (size_t)(m0 + row) * K + (col >> 1);
    adst[i] = i * 8192 + wid * 1024;
  }
  const f16* bsrc[2]; int bdst[2];
  #pragma unroll
  for (int i = 0; i < 2; ++i) {
    int p = i * 8192 + tid * 16;
    int row = p >> 7;
    int col = (p & 127) ^ ((row & 7) << 4);
    bsrc[i] = B + (size_t)(n0 + row) * K + (col >> 1);
    bdst[i] = i * 8192 + wid * 1024;
  }

  f32x4 acc[4][4] = {};

  #pragma unroll
  for (int i = 0; i < 4; ++i) gload16(asrc[i], sm + adst[i]);
  #pragma unroll
  for (int i = 0; i < 2; ++i) gload16(bsrc[i], sm + 98304 + bdst[i]);
  #pragma unroll
  for (int i = 0; i < 4; ++i) gload16(asrc[i] + 64, sm + 32768 + adst[i]);
  #pragma unroll
  for (int i = 0; i < 2; ++i) gload16(bsrc[i] + 64, sm + 98304 + 16384 + bdst[i]);

  for (int kt = 0; kt < 16; ++kt) {
    if (kt < 15) asm volatile("s_waitcnt vmcnt(6)" ::: "memory");
    else         asm volatile("s_waitcnt vmcnt(0)" ::: "memory");
    __builtin_amdgcn_s_barrier();

    int j = kt % 3;
    char* As = sm + j * 32768;
    char* Bs = sm + 98304 + j * 16384;
    int jn = (kt + 2) % 3;
    char* Ad = sm + jn * 32768;
    char* Bd = sm + 98304 + jn * 16384;
    bool stg = (kt <= 13);

    if (stg) {
      gload16(asrc[0] + (kt + 2) * 64, Ad + adst[0]);
      gload16(asrc[1] + (kt + 2) * 64, Ad + adst[1]);
      gload16(asrc[2] + (kt + 2) * 64, Ad + adst[2]);
    }
    {
      int co = (g * 16) ^ swz;
      f16x8 af[4], bf[4];
      #pragma unroll
      for (int fr = 0; fr < 4; ++fr)
        af[fr] = *(const f16x8*)(As + (wm * 64 + fr * 16 + c) * 128 + co);
      #pragma unroll
      for (int fn = 0; fn < 4; ++fn)
        bf[fn] = *(const f16x8*)(Bs + (wn * 64 + fn * 16 + c) * 128 + co);
      __builtin_amdgcn_s_setprio(1);
      #pragma unroll
      for (int fr = 0; fr < 4; ++fr)
        #pragma unroll
        for (int fn = 0; fn < 4; ++fn)
          acc[fr][fn] = __builtin_amdgcn_mfma_f32_16x16x32_f16(af[fr], bf[fn], acc[fr][fn], 0, 0, 0);
      __builtin_amdgcn_s_setprio(0);
    }
    if (stg) {
      gload16(asrc[3] + (kt + 2) * 64, Ad + adst[3]);
      gload16(bsrc[0] + (kt + 2) * 64, Bd + bdst[0]);
      gload16(bsrc[1] + (kt + 2) * 64, Bd + bdst[1]);
    }
    {
      int co = (64 + g * 16) ^ swz;
      f16x8 af[4], bf[4];
      #pragma unroll
      for (int fr = 0; fr < 4; ++fr)
        af[fr] = *(const f16x8*)(As + (wm * 64 + fr * 16 + c) * 128 + co);
      #pragma unroll
      for (int fn = 0; fn < 4; ++fn)
        bf[fn] = *(const f16x8*)(Bs + (wn * 64 + fn * 16 + c) * 128 + co);
      __builtin_amdgcn_s_setprio(1);
      #pragma unroll
      for (int fr = 0; fr < 4; ++fr)
        #pragma unroll
        for (int fn = 0; fn < 4; ++fn)
          acc[fr][fn] = __builtin_amdgcn_mfma_f32_16x16x32_f16(af[fr], bf[fn], acc[fr][fn], 0, 0, 0);
      __builtin_amdgcn_s_setprio(0);
    }
  }

  int which = n0 >> 10;
  #pragma unroll
  for (int fr = 0; fr < 4; ++fr) {
    int m = m0 + wm * 64 + fr * 16 + g * 4;
    int b = m >> 11, t = m & 2047;
    #pragma unroll
    for (int fn = 0; fn < 4; ++fn) {
      int n = n0 + wn * 64 + fn * 16 + c;
      int nf = n & 1023, hh = nf >> 6, d = nf & 63;
      if (which == 0) {
        #pragma unroll
        for (int r = 0; r < 4; ++r)
          Q[(size_t)((b * 16 + hh) * 2048 + (t + r)) * 64 + d] = (f16)(acc[fr][fn][r] * 0.180336880111f);
      } else if (which == 1) {
        #pragma unroll
        for (int r = 0; r < 4; ++r)
          Kh[(size_t)((b * 16 + hh) * 2048 + (t + r)) * 64 + d] = (f16)acc[fr][fn][r];
      } else {
        uint2 pk;
        pk.x = packh2(acc[fr][fn][0], acc[fr][fn][1]);
        pk.y = packh2(acc[fr][fn][2], acc[fr][fn][3]);
        *(uint2*)(Vt + (size_t)((b * 16 + hh) * 64 + d) * 2048 + t) = pk;
      }
    }
  }
}

// ---------------- GEMM2: out = AO @ Wout^T (fp32 out) ----------------

__global__ __launch_bounds__(512, 2) void gemm_out(const f16* __restrict__ A,
                                                   const f16* __restrict__ B,
                                                   float* __restrict__ Cout) {
  __shared__ __align__(16) char sm[147456];
  const int K = 1024;
  int tid = threadIdx.x;
  int lane = tid & 63, wid = tid >> 6;
  int bid = blockIdx.x;
  int xcd = bid & 7;
  int id = bid >> 3;
  int m0 = (xcd * 4 + id / 8) * 256;
  int n0 = (id & 7) * 128;
  int wm = wid >> 1, wn = wid & 1;
  int c = lane & 15, g = lane >> 4;
  int swz = (c & 7) << 4;

  const f16* asrc[4]; int adst[4];
  #pragma unroll
  for (int i = 0; i < 4; ++i) {
    int p = i * 8192 + tid * 16;
    int row = p >> 7;
    int col = (p & 127) ^ ((row & 7) << 4);
    asrc[i] = A + (size_t)(m0 + row) * K + (col >> 1);
    adst[i] = i * 8192 + wid * 1024;
  }
  const f16* bsrc[2]; int bdst[2];
  #pragma unroll
  for (int i = 0; i < 2; ++i) {
    int p = i * 8192 + tid * 16;
    int row = p >> 7;
    int col = (p & 127) ^ ((row & 7) << 4);
    bsrc[i] = B + (size_t)(n0 + row) * K + (col >> 1);
    bdst[i] = i * 8192 + wid * 1024;
  }

  f32x4 acc[4][4] = {};

  #pragma unroll
  for (int i = 0; i < 4; ++i) gload16(asrc[i], sm + adst[i]);
  #pragma unroll
  for (int i = 0; i < 2; ++i) gload16(bsrc[i], sm + 98304 + bdst[i]);
  #pragma unroll
  for (int i = 0; i < 4; ++i) gload16(asrc[i] + 64, sm + 32768 + adst[i]);
  #pragma unroll
  for (int i = 0; i < 2; ++i) gload16(bsrc[i] + 64, sm + 98304 + 16384 + bdst[i]);

  for (int kt = 0; kt < 16; ++kt) {
    if (kt < 15) asm volatile("s_waitcnt vmcnt(6)" ::: "memory");
    else         asm volatile("s_waitcnt vmcnt(0)" ::: "memory");
    __builtin_amdgcn_s_barrier();

    int j = kt % 3;
    char* As = sm + j * 32768;
    char* Bs = sm + 98304 + j * 16384;
    int jn = (kt + 2) % 3;
    char* Ad = sm + jn * 32768;
    char* Bd = sm + 98304 + jn * 16384;
    bool stg = (kt <= 13);

    if (stg) {
      gload16(asrc[0] + (kt + 2) * 64, Ad + adst[0]);
      gload16(asrc[1] + (kt + 2) * 64, Ad + adst[1]);
      gload16(asrc[2] + (kt + 2) * 64, Ad + adst[2]);
    }
    {
      int co = (g * 16) ^ swz;
      f16x8 af[4], bf[4];
      #pragma unroll
      for (int fr = 0; fr < 4; ++fr)
        af[fr] = *(const f16x8*)(As + (wm * 64 + fr * 16 + c) * 128 + co);
      #pragma unroll
      for (int fn = 0; fn < 4; ++fn)
        bf[fn] = *(const f16x8*)(Bs + (wn * 64 + fn * 16 + c) * 128 + co);
      __builtin_amdgcn_s_setprio(1);
      #pragma unroll
      for (int fr = 0; fr < 4; ++fr)
        #pragma unroll
        for (int fn = 0; fn < 4; ++fn)
          acc[fr][fn] = __builtin_amdgcn_mfma_f32_16x16x32_f16(af[fr], bf[fn], acc[fr][fn], 0, 0, 0);
      __builtin_amdgcn_s_setprio(0);
    }
    if (stg) {
      gload16(asrc[3] + (kt + 2) * 64, Ad + adst[3]);
      gload16(bsrc[0] + (kt + 2) * 64, Bd + bdst[0]);
      gload16(bsrc[1] + (kt + 2) * 64, Bd + bdst[1]);
    }
    {
      int co = (64 + g * 16) ^ swz;
      f16x8 af[4], bf[4];
      #pragma unroll
      for (int fr = 0; fr < 4; ++fr)
        af[fr] = *(const f16x8*)(As + (wm * 64 + fr * 16 + c) * 128 + co);
      #pragma unroll
      for (int fn = 0; fn < 4; ++fn)
        bf[fn] = *(const f16x8*)(Bs + (wn * 64 + fn * 16 + c) * 128 + co);
      __builtin_amdgcn_s_setprio(1);
      #pragma unroll
      for (int fr = 0; fr < 4; ++fr)
        #pragma unroll
        for (int fn = 0; fn < 4; ++fn)
          acc[fr][fn] = __builtin_amdgcn_mfma_f32_16x16x32_f16(af[fr], bf[fn], acc[fr][fn], 0, 0, 0);
      __builtin_amdgcn_s_setprio(0);
    }
  }

  #pragma unroll
  for (int fr = 0; fr < 4; ++fr) {
    int m = m0 + wm * 64 + fr * 16 + g * 4;
    #pragma unroll
    for (int fn = 0; fn < 4; ++fn) {
      int n = n0 + wn * 64 + fn * 16 + c;
      #pragma unroll
      for (int r = 0; r < 4; ++r)
        Cout[(size_t)(m + r) * 1024 + n] = acc[fr][fn][r];
    }
  }
}

// ---------------- flash attention (4 waves, q-tile 128, KVBLK 64) ----------
// __launch_bounds__(256, 4): 4 waves/SIMD. LDS 40KB (K dbuf 2x16K + V single
// 8K) -> 4 blocks/CU = 160KB exactly. V(kt) issued at iter-top, consumed by
// PV(kt) after mid-iter {vmcnt(4); s_barrier} (V loads issued before K loads
// so FIFO retires them at count 4; final iter has no K -> vmcnt(0)).
// Balanced qt permutation: each CU's 4 round-robin-resident blocks sum to a
// constant 68 kv-iter units (no queue slack at 4 blocks/CU).

__global__ __launch_bounds__(256, 4) void attn(const f16* __restrict__ Q,
                                               const f16* __restrict__ Kh,
                                               const f16* __restrict__ Vt,
                                               const f16* __restrict__ U,
                                               const f16* __restrict__ Wt,
                                               f16* __restrict__ AO) {
  __shared__ __align__(16) char sm[40960];   // K0 16K | K1 16K | V 8K
  int tid = threadIdx.x, lane = tid & 63, wid = tid >> 6;   // 4 waves
  int l31 = lane & 31, hi = lane >> 5;
  int o = blockIdx.x;
  int bq = o >> 6;
  int rr = bq & 3, g2 = bq >> 2;
  int qt = (g2 == 0) ? 15 - 2 * rr
         : (g2 == 1) ? 2 * rr
         : (g2 == 2) ? 14 - 2 * rr
                     : 2 * rr + 1;
  int bh = o & 63;
  int h = bh & 15, b = bh >> 4;
  int swzK = (lane & 15) << 4;     // K' rows 256B
  int swzV = (lane & 7) << 4;      // V rows 128B

  // K' staging: 64 rows x 256B = 16KB -> 4 sweeps of 4KB
  const f16* ksrc[4]; int kdst[4];
  #pragma unroll
  for (int i = 0; i < 4; ++i) {
    int p = i * 4096 + tid * 16;
    int row = p >> 8;                        // 0..63
    int col = (p & 255) ^ ((row & 15) << 4);
    int ce = col >> 1;
    ksrc[i] = (ce < 64) ? (Kh + (size_t)(bh * 2048 + row) * 64 + ce)
                        : (Wt + (size_t)(h * 2048 + row) * 64 + (ce - 64));
    kdst[i] = i * 4096 + wid * 1024;
  }
  // V staging: 64 d-rows x 128B (64 kv) = 8KB -> 2 sweeps
  const f16* vsrc[2]; int vdst[2];
  #pragma unroll
  for (int i = 0; i < 2; ++i) {
    int p = i * 4096 + tid * 16;
    int row = p >> 7;                        // 0..63
    int col = (p & 127) ^ ((row & 7) << 4);
    vsrc[i] = Vt + (size_t)(bh * 64 + row) * 2048 + (col >> 1);
    vdst[i] = i * 4096 + wid * 1024;
  }

  int qrow = qt * 128 + wid * 32 + l31;
  int ktmax = 2 * qt + 1;

  // Q' fragments: k = ks*16 + hi*8 + [0..8); ks 0-3 from Q, 4-7 from U
  f16x8 qf[8];
  {
    const f16* qp = Q + (size_t)(bh * 2048 + qrow) * 64 + hi * 8;
    const f16* up = U + (size_t)qrow * 64 + hi * 8;
    #pragma unroll
    for (int ks = 0; ks < 4; ++ks) {
      qf[ks]     = *(const f16x8*)(qp + ks * 16);
      qf[4 + ks] = *(const f16x8*)(up + ks * 16);
    }
  }

  float m_i = -1e30f, l_i = 0.0f;
  f32x16 accA = {}, accB = {};

  // prologue: stage K(0) -> K0 and V(0) -> Vbuf
  #pragma unroll
  for (int i = 0; i < 4; ++i) gload16(ksrc[i], sm + kdst[i]);
  #pragma unroll
  for (int i = 0; i < 2; ++i) gload16(vsrc[i], sm + 32768 + vdst[i]);
  __syncthreads();

  for (int kt = 0; kt <= ktmax; ++kt) {
    char* Ks = sm + (kt & 1) * 16384;
    char* Vs = sm + 32768;

    // issue V(kt) first (kt>=1; V(0) staged in prologue), then K(kt+1):
    // FIFO order lets vmcnt(4) retire exactly the V loads.
    if (kt >= 1) {
      #pragma unroll
      for (int i = 0; i < 2; ++i) gload16(vsrc[i] + (size_t)kt * 64, Vs + vdst[i]);
    }
    bool hasK = (kt < ktmax);
    if (hasK) {
      char* kb = sm + ((kt + 1) & 1) * 16384;
      #pragma unroll
      for (int i = 0; i < 4; ++i) gload16(ksrc[i] + (size_t)(kt + 1) * 4096, kb + kdst[i]);
    }

    // S^T = K' @ Q'^T : st0 = kv[0,32), st1 = kv[32,64)
    f32x16 st0 = {}, st1 = {};
    __builtin_amdgcn_s_setprio(1);
    #pragma unroll
    for (int ks = 0; ks < 8; ++ks) {
      int co = (ks * 32 + hi * 16) ^ swzK;
      f16x8 k0 = *(const f16x8*)(Ks + l31 * 256 + co);
      f16x8 k1 = *(const f16x8*)(Ks + (32 + l31) * 256 + co);
      st0 = __builtin_amdgcn_mfma_f32_32x32x16_f16(k0, qf[ks], st0, 0, 0, 0);
      st1 = __builtin_amdgcn_mfma_f32_32x32x16_f16(k1, qf[ks], st1, 0, 0, 0);
    }
    __builtin_amdgcn_s_setprio(0);

    int kv0 = kt * 64;
    if (kv0 + 63 > qt * 128 + wid * 32) {   // wave-uniform branch
      #pragma unroll
      for (int r = 0; r < 16; ++r) {
        int kvl = kv0 + (r & 3) + 8 * (r >> 2) + 4 * hi;
        if (kvl > qrow) st0[r] = -1e30f;
        if (kvl + 32 > qrow) st1[r] = -1e30f;
      }
    }

    // online softmax in exp2 space, defer-max (THR = 8)
    float pm = fmaxf(st0[0], st1[0]);
    #pragma unroll
    for (int r = 1; r < 16; ++r) pm = max3f(pm, st0[r], st1[r]);
    pm = fmaxf(pm, __shfl_xor(pm, 32, 64));
    if (!__all(pm <= m_i + 8.0f)) {
      float mnew = fmaxf(m_i, pm);
      float sc = __builtin_amdgcn_exp2f(m_i - mnew);
      l_i *= sc;
      accA *= sc;
      accB *= sc;
      m_i = mnew;
    }

    float ps = 0.0f;
    u32 pk0[8], pk1[8];
    #pragma unroll
    for (int j = 0; j < 8; ++j) {
      float a0 = __builtin_amdgcn_exp2f(st0[2 * j] - m_i);
      float a1 = __builtin_amdgcn_exp2f(st0[2 * j + 1] - m_i);
      float b0 = __builtin_amdgcn_exp2f(st1[2 * j] - m_i);
      float b1 = __builtin_amdgcn_exp2f(st1[2 * j + 1] - m_i);
      ps += (a0 + a1) + (b0 + b1);
      pk0[j] = pkrtz(a0, a1);
      pk1[j] = pkrtz(b0, b1);
    }
    ps += __shfl_xor(ps, 32, 64);
    l_i += ps;

    // redistribute P into PV B-fragments
    pl32swap(pk0[0], pk0[2]); pl32swap(pk0[1], pk0[3]);
    pl32swap(pk0[4], pk0[6]); pl32swap(pk0[5], pk0[7]);
    pl32swap(pk1[0], pk1[2]); pl32swap(pk1[1], pk1[3]);
    pl32swap(pk1[4], pk1[6]); pl32swap(pk1[5], pk1[7]);

    // V(kt) ready gate: retire the 2 V loads (4 K loads may stay in flight)
    if (hasK) asm volatile("s_waitcnt vmcnt(4)" ::: "memory");
    else      asm volatile("s_waitcnt vmcnt(0)" ::: "memory");
    __builtin_amdgcn_s_barrier();

    // PV: O^T += V^T @ P^T (4 kb-steps over 64 kv)
    __builtin_amdgcn_s_setprio(1);
    #pragma unroll
    for (int kb = 0; kb < 4; ++kb) {
      union { u32 w[4]; f16x8 v; } bf;
      const u32* pk = (kb < 2) ? pk0 : pk1;
      int base = (kb & 1) * 4;
      bf.w[0] = pk[base + 0]; bf.w[1] = pk[base + 1];
      bf.w[2] = pk[base + 2]; bf.w[3] = pk[base + 3];
      int co = (kb * 32 + hi * 16) ^ swzV;
      f16x8 v0 = *(const f16x8*)(Vs + l31 * 128 + co);
      f16x8 v1 = *(const f16x8*)(Vs + (32 + l31) * 128 + co);
      accA = __builtin_amdgcn_mfma_f32_32x32x16_f16(v0, bf.v, accA, 0, 0, 0);
      accB = __builtin_amdgcn_mfma_f32_32x32x16_f16(v1, bf.v, accB, 0, 0, 0);
    }
    __builtin_amdgcn_s_setprio(0);
    __syncthreads();
  }

  // epilogue: O[q][d] = acc^T / l
  float inv = __builtin_amdgcn_rcpf(l_i);
  f16* aop = AO + (size_t)(b * 2048 + qrow) * 1024 + h * 64;
  #pragma unroll
  for (int u = 0; u < 4; ++u) {
    uint2 ov;
    ov.x = pkrtz(accA[4 * u] * inv, accA[4 * u + 1] * inv);
    ov.y = pkrtz(accA[4 * u + 2] * inv, accA[4 * u + 3] * inv);
    *(uint2*)(aop + 8 * u + 4 * hi) = ov;
    ov.x = pkrtz(accB[4 * u] * inv, accB[4 * u + 1] * inv);
    ov.y = pkrtz(accB[4 * u + 2] * inv, accB[4 * u + 3] * inv);
    *(uint2*)(aop + 32 + 8 * u + 4 * hi) = ov;
  }
}

// ---------------- launcher ----------------

extern "C" void kernel_launch(void* const* d_in, const int* in_sizes, int n_in,
                              void* d_out, int out_size, void* d_ws, size_t ws_size,
                              hipStream_t stream) {
  const float* x     = (const float*)d_in[0];
  const float* Wqkv  = (const float*)d_in[1];
  const float* Wout  = (const float*)d_in[2];
  const float* alpha = (const float*)d_in[3];
  const float* beta  = (const float*)d_in[4];

  char* ws = (char*)d_ws;
  f16* Xh    = (f16*)(ws);                  // 16 MiB  (later reused as AO)
  f16* Wqkvh = (f16*)(ws + 16777216);       // 6 MiB
  f16* Wouth = (f16*)(ws + 23068672);       // 2 MiB
  f16* Qh    = (f16*)(ws + 25165824);       // 16 MiB
  f16* Kh    = (f16*)(ws + 41943040);       // 16 MiB
  f16* Vt    = (f16*)(ws + 58720256);       // 16 MiB
  f16* U     = (f16*)(ws + 75497472);       // 256 KiB
  f16* Wt    = (f16*)(ws + 75759616);       // 4 MiB
  f16* AO    = Xh;

  cvt_f32_f16<<<4096, 256, 0, stream>>>(x, Xh, 8388608);
  cvt_f32_f16<<<1536, 256, 0, stream>>>(Wqkv, Wqkvh, 3145728);
  cvt_f32_f16<<<512, 256, 0, stream>>>(Wout, Wouth, 1048576);
  build_tables<<<256, 256, 0, stream>>>(alpha, beta, U, Wt);
  gemm_qkv<<<768, 512, 0, stream>>>(Xh, Wqkvh, Qh, Kh, Vt);
  attn<<<1024, 256, 0, stream>>>(Qh, Kh, Vt, U, Wt, AO);
  gemm_out<<<256, 512, 0, stream>>>(AO, Wouth, (float*)d_out);
}

// Round 19
// 162.908 us; speedup vs baseline: 1.1281x; 1.1281x over previous
//
#include <hip/hip_runtime.h>
#include <cstdint>
#include <cstddef>

typedef _Float16 f16;
typedef f16 f16x8 __attribute__((ext_vector_type(8)));
typedef __fp16 fp16x2 __attribute__((ext_vector_type(2)));
typedef float f32x4 __attribute__((ext_vector_type(4)));
typedef float f32x16 __attribute__((ext_vector_type(16)));
typedef uint32_t u32;

// ---------------- helpers ----------------

__device__ __forceinline__ void gload16(const void* g, void* l) {
  __builtin_amdgcn_global_load_lds((const __attribute__((address_space(1))) void*)g,
                                   (__attribute__((address_space(3))) void*)l,
                                   16u, 0, 0u);
}

__device__ __forceinline__ u32 pkrtz(float a, float b) {
  union { fp16x2 v; u32 u; } t;
  t.v = __builtin_amdgcn_cvt_pkrtz(a, b);
  return t.u;
}

__device__ __forceinline__ u32 packh2(float a, float b) { return pkrtz(a, b); }

__device__ __forceinline__ float max3f(float a, float b, float c) {
  return fmaxf(fmaxf(a, b), c);
}

// exchange halves between a and b (used ONLY with distance>=8 from writes of
// its inputs -- VALU->permlane hazard; see R7 post-mortem)
__device__ __forceinline__ void pl32swap(u32& a, u32& b) {
  asm volatile("v_permlane32_swap_b32 %0, %1" : "+v"(a), "+v"(b));
}

// ---------------- fp32 -> fp16 convert ----------------

__global__ __launch_bounds__(256) void cvt_f32_f16(const float* __restrict__ in,
                                                   f16* __restrict__ out, int n) {
  int i = (blockIdx.x * 256 + threadIdx.x) * 8;
  if (i >= n) return;
  float4 a = *(const float4*)(in + i);
  float4 b = *(const float4*)(in + i + 4);
  f16x8 o;
  o[0] = (f16)a.x; o[1] = (f16)a.y; o[2] = (f16)a.z; o[3] = (f16)a.w;
  o[4] = (f16)b.x; o[5] = (f16)b.y; o[6] = (f16)b.z; o[7] = (f16)b.w;
  *(f16x8*)(out + i) = o;
}

// ---------------- bias factor tables ----------------

__global__ __launch_bounds__(256) void build_tables(const float* __restrict__ alpha,
                                                    const float* __restrict__ beta,
                                                    f16* __restrict__ U,
                                                    f16* __restrict__ Wt) {
  int idx = blockIdx.x * 256 + threadIdx.x;   // t*32 + r
  int t = idx >> 5, r = idx & 31;
  float w = powf(10000.0f, -(float)r / 32.0f);
  float ang = w * (float)t;
  float c = cosf(ang), s = sinf(ang);
  const float L2E = 1.44269504089f;
  U[t * 64 + 2 * r]     = (f16)(c * L2E);
  U[t * 64 + 2 * r + 1] = (f16)(s * L2E);
  #pragma unroll
  for (int h = 0; h < 16; ++h) {
    float al = alpha[h * 32 + r], be = beta[h * 32 + r];
    Wt[(size_t)(h * 2048 + t) * 64 + 2 * r]     = (f16)(al * c - be * s);
    Wt[(size_t)(h * 2048 + t) * 64 + 2 * r + 1] = (f16)(al * s + be * c);
  }
}

// ---------------- GEMM core (BM=256, BN=128, BK=64, 8 waves) ----------
// m-major-per-XCD partition (R14, proven).

__global__ __launch_bounds__(512, 2) void gemm_qkv(const f16* __restrict__ A,
                                                   const f16* __restrict__ B,
                                                   f16* __restrict__ Q,
                                                   f16* __restrict__ Kh,
                                                   f16* __restrict__ Vt) {
  __shared__ __align__(16) char sm[147456];
  const int K = 1024;
  int tid = threadIdx.x;
  int lane = tid & 63, wid = tid >> 6;
  int bid = blockIdx.x;
  int xcd = bid & 7;
  int id = bid >> 3;
  int ml = id / 24;
  int nn = id % 24;
  int m0 = (xcd * 4 + ml) * 256;
  int n0 = nn * 128;
  int wm = wid >> 1, wn = wid & 1;
  int c = lane & 15, g = lane >> 4;
  int swz = (c & 7) << 4;

  const f16* asrc[4]; int adst[4];
  #pragma unroll
  for (int i = 0; i < 4; ++i) {
    int p = i * 8192 + tid * 16;
    int row = p >> 7;
    int col = (p & 127) ^ ((row & 7) << 4);
    asrc[i] = A + (size_t)(m0 + row) * K + (col >> 1);
    adst[i] = i * 8192 + wid * 1024;
  }
  const f16* bsrc[2]; int bdst[2];
  #pragma unroll
  for (int i = 0; i < 2; ++i) {
    int p = i * 8192 + tid * 16;
    int row = p >> 7;
    int col = (p & 127) ^ ((row & 7) << 4);
    bsrc[i] = B + (size_t)(n0 + row) * K + (col >> 1);
    bdst[i] = i * 8192 + wid * 1024;
  }

  f32x4 acc[4][4] = {};

  #pragma unroll
  for (int i = 0; i < 4; ++i) gload16(asrc[i], sm + adst[i]);
  #pragma unroll
  for (int i = 0; i < 2; ++i) gload16(bsrc[i], sm + 98304 + bdst[i]);
  #pragma unroll
  for (int i = 0; i < 4; ++i) gload16(asrc[i] + 64, sm + 32768 + adst[i]);
  #pragma unroll
  for (int i = 0; i < 2; ++i) gload16(bsrc[i] + 64, sm + 98304 + 16384 + bdst[i]);

  for (int kt = 0; kt < 16; ++kt) {
    if (kt < 15) asm volatile("s_waitcnt vmcnt(6)" ::: "memory");
    else         asm volatile("s_waitcnt vmcnt(0)" ::: "memory");
    __builtin_amdgcn_s_barrier();

    int j = kt % 3;
    char* As = sm + j * 32768;
    char* Bs = sm + 98304 + j * 16384;
    int jn = (kt + 2) % 3;
    char* Ad = sm + jn * 32768;
    char* Bd = sm + 98304 + jn * 16384;
    bool stg = (kt <= 13);

    if (stg) {
      gload16(asrc[0] + (kt + 2) * 64, Ad + adst[0]);
      gload16(asrc[1] + (kt + 2) * 64, Ad + adst[1]);
      gload16(asrc[2] + (kt + 2) * 64, Ad + adst[2]);
    }
    {
      int co = (g * 16) ^ swz;
      f16x8 af[4], bf[4];
      #pragma unroll
      for (int fr = 0; fr < 4; ++fr)
        af[fr] = *(const f16x8*)(As + (wm * 64 + fr * 16 + c) * 128 + co);
      #pragma unroll
      for (int fn = 0; fn < 4; ++fn)
        bf[fn] = *(const f16x8*)(Bs + (wn * 64 + fn * 16 + c) * 128 + co);
      __builtin_amdgcn_s_setprio(1);
      #pragma unroll
      for (int fr = 0; fr < 4; ++fr)
        #pragma unroll
        for (int fn = 0; fn < 4; ++fn)
          acc[fr][fn] = __builtin_amdgcn_mfma_f32_16x16x32_f16(af[fr], bf[fn], acc[fr][fn], 0, 0, 0);
      __builtin_amdgcn_s_setprio(0);
    }
    if (stg) {
      gload16(asrc[3] + (kt + 2) * 64, Ad + adst[3]);
      gload16(bsrc[0] + (kt + 2) * 64, Bd + bdst[0]);
      gload16(bsrc[1] + (kt + 2) * 64, Bd + bdst[1]);
    }
    {
      int co = (64 + g * 16) ^ swz;
      f16x8 af[4], bf[4];
      #pragma unroll
      for (int fr = 0; fr < 4; ++fr)
        af[fr] = *(const f16x8*)(As + (wm * 64 + fr * 16 + c) * 128 + co);
      #pragma unroll
      for (int fn = 0; fn < 4; ++fn)
        bf[fn] = *(const f16x8*)(Bs + (wn * 64 + fn * 16 + c) * 128 + co);
      __builtin_amdgcn_s_setprio(1);
      #pragma unroll
      for (int fr = 0; fr < 4; ++fr)
        #pragma unroll
        for (int fn = 0; fn < 4; ++fn)
          acc[fr][fn] = __builtin_amdgcn_mfma_f32_16x16x32_f16(af[fr], bf[fn], acc[fr][fn], 0, 0, 0);
      __builtin_amdgcn_s_setprio(0);
    }
  }

  int which = n0 >> 10;
  #pragma unroll
  for (int fr = 0; fr < 4; ++fr) {
    int m = m0 + wm * 64 + fr * 16 + g * 4;
    int b = m >> 11, t = m & 2047;
    #pragma unroll
    for (int fn = 0; fn < 4; ++fn) {
      int n = n0 + wn * 64 + fn * 16 + c;
      int nf = n & 1023, hh = nf >> 6, d = nf & 63;
      if (which == 0) {
        #pragma unroll
        for (int r = 0; r < 4; ++r)
          Q[(size_t)((b * 16 + hh) * 2048 + (t + r)) * 64 + d] = (f16)(acc[fr][fn][r] * 0.180336880111f);
      } else if (which == 1) {
        #pragma unroll
        for (int r = 0; r < 4; ++r)
          Kh[(size_t)((b * 16 + hh) * 2048 + (t + r)) * 64 + d] = (f16)acc[fr][fn][r];
      } else {
        uint2 pk;
        pk.x = packh2(acc[fr][fn][0], acc[fr][fn][1]);
        pk.y = packh2(acc[fr][fn][2], acc[fr][fn][3]);
        *(uint2*)(Vt + (size_t)((b * 16 + hh) * 64 + d) * 2048 + t) = pk;
      }
    }
  }
}

// ---------------- GEMM2: out = AO @ Wout^T (fp32 out) ----------------

__global__ __launch_bounds__(512, 2) void gemm_out(const f16* __restrict__ A,
                                                   const f16* __restrict__ B,
                                                   float* __restrict__ Cout) {
  __shared__ __align__(16) char sm[147456];
  const int K = 1024;
  int tid = threadIdx.x;
  int lane = tid & 63, wid = tid >> 6;
  int bid = blockIdx.x;
  int xcd = bid & 7;
  int id = bid >> 3;
  int m0 = (xcd * 4 + id / 8) * 256;
  int n0 = (id & 7) * 128;
  int wm = wid >> 1, wn = wid & 1;
  int c = lane & 15, g = lane >> 4;
  int swz = (c & 7) << 4;

  const f16* asrc[4]; int adst[4];
  #pragma unroll
  for (int i = 0; i < 4; ++i) {
    int p = i * 8192 + tid * 16;
    int row = p >> 7;
    int col = (p & 127) ^ ((row & 7) << 4);
    asrc[i] = A + (size_t)(m0 + row) * K + (col >> 1);
    adst[i] = i * 8192 + wid * 1024;
  }
  const f16* bsrc[2]; int bdst[2];
  #pragma unroll
  for (int i = 0; i < 2; ++i) {
    int p = i * 8192 + tid * 16;
    int row = p >> 7;
    int col = (p & 127) ^ ((row & 7) << 4);
    bsrc[i] = B + (size_t)(n0 + row) * K + (col >> 1);
    bdst[i] = i * 8192 + wid * 1024;
  }

  f32x4 acc[4][4] = {};

  #pragma unroll
  for (int i = 0; i < 4; ++i) gload16(asrc[i], sm + adst[i]);
  #pragma unroll
  for (int i = 0; i < 2; ++i) gload16(bsrc[i], sm + 98304 + bdst[i]);
  #pragma unroll
  for (int i = 0; i < 4; ++i) gload16(asrc[i] + 64, sm + 32768 + adst[i]);
  #pragma unroll
  for (int i = 0; i < 2; ++i) gload16(bsrc[i] + 64, sm + 98304 + 16384 + bdst[i]);

  for (int kt = 0; kt < 16; ++kt) {
    if (kt < 15) asm volatile("s_waitcnt vmcnt(6)" ::: "memory");
    else         asm volatile("s_waitcnt vmcnt(0)" ::: "memory");
    __builtin_amdgcn_s_barrier();

    int j = kt % 3;
    char* As = sm + j * 32768;
    char* Bs = sm + 98304 + j * 16384;
    int jn = (kt + 2) % 3;
    char* Ad = sm + jn * 32768;
    char* Bd = sm + 98304 + jn * 16384;
    bool stg = (kt <= 13);

    if (stg) {
      gload16(asrc[0] + (kt + 2) * 64, Ad + adst[0]);
      gload16(asrc[1] + (kt + 2) * 64, Ad + adst[1]);
      gload16(asrc[2] + (kt + 2) * 64, Ad + adst[2]);
    }
    {
      int co = (g * 16) ^ swz;
      f16x8 af[4], bf[4];
      #pragma unroll
      for (int fr = 0; fr < 4; ++fr)
        af[fr] = *(const f16x8*)(As + (wm * 64 + fr * 16 + c) * 128 + co);
      #pragma unroll
      for (int fn = 0; fn < 4; ++fn)
        bf[fn] = *(const f16x8*)(Bs + (wn * 64 + fn * 16 + c) * 128 + co);
      __builtin_amdgcn_s_setprio(1);
      #pragma unroll
      for (int fr = 0; fr < 4; ++fr)
        #pragma unroll
        for (int fn = 0; fn < 4; ++fn)
          acc[fr][fn] = __builtin_amdgcn_mfma_f32_16x16x32_f16(af[fr], bf[fn], acc[fr][fn], 0, 0, 0);
      __builtin_amdgcn_s_setprio(0);
    }
    if (stg) {
      gload16(asrc[3] + (kt + 2) * 64, Ad + adst[3]);
      gload16(bsrc[0] + (kt + 2) * 64, Bd + bdst[0]);
      gload16(bsrc[1] + (kt + 2) * 64, Bd + bdst[1]);
    }
    {
      int co = (64 + g * 16) ^ swz;
      f16x8 af[4], bf[4];
      #pragma unroll
      for (int fr = 0; fr < 4; ++fr)
        af[fr] = *(const f16x8*)(As + (wm * 64 + fr * 16 + c) * 128 + co);
      #pragma unroll
      for (int fn = 0; fn < 4; ++fn)
        bf[fn] = *(const f16x8*)(Bs + (wn * 64 + fn * 16 + c) * 128 + co);
      __builtin_amdgcn_s_setprio(1);
      #pragma unroll
      for (int fr = 0; fr < 4; ++fr)
        #pragma unroll
        for (int fn = 0; fn < 4; ++fn)
          acc[fr][fn] = __builtin_amdgcn_mfma_f32_16x16x32_f16(af[fr], bf[fn], acc[fr][fn], 0, 0, 0);
      __builtin_amdgcn_s_setprio(0);
    }
  }

  #pragma unroll
  for (int fr = 0; fr < 4; ++fr) {
    int m = m0 + wm * 64 + fr * 16 + g * 4;
    #pragma unroll
    for (int fn = 0; fn < 4; ++fn) {
      int n = n0 + wn * 64 + fn * 16 + c;
      #pragma unroll
      for (int r = 0; r < 4; ++r)
        Cout[(size_t)(m + r) * 1024 + n] = acc[fr][fn][r];
    }
  }
}

// ---------------- flash attention (4 waves, q-tile 128, KVBLK 64) ----------
// __launch_bounds__(256, 3): 3 waves/SIMD (proven 76.5 us; 4 waves spills --
// R18). 48KB LDS x 3 blocks = 144KB. Grid 1024, big tiles first, o&63=bh
// keeps XCD pinning. Internals = proven R8/R16 attn.

__global__ __launch_bounds__(256, 3) void attn(const f16* __restrict__ Q,
                                               const f16* __restrict__ Kh,
                                               const f16* __restrict__ Vt,
                                               const f16* __restrict__ U,
                                               const f16* __restrict__ Wt,
                                               f16* __restrict__ AO) {
  __shared__ __align__(16) char sm[49152];   // K' 2x16K | V 2x8K
  int tid = threadIdx.x, lane = tid & 63, wid = tid >> 6;   // 4 waves
  int l31 = lane & 31, hi = lane >> 5;
  int o = blockIdx.x;
  int qt = 15 - (o >> 6);          // big tiles first
  int bh = o & 63;
  int h = bh & 15, b = bh >> 4;
  int swzK = (lane & 15) << 4;     // K' rows 256B
  int swzV = (lane & 7) << 4;      // V rows 128B

  // K' staging: 64 rows x 256B = 16KB -> 4 sweeps of 4KB
  const f16* ksrc[4]; int kdst[4];
  #pragma unroll
  for (int i = 0; i < 4; ++i) {
    int p = i * 4096 + tid * 16;
    int row = p >> 8;                        // 0..63
    int col = (p & 255) ^ ((row & 15) << 4);
    int ce = col >> 1;
    ksrc[i] = (ce < 64) ? (Kh + (size_t)(bh * 2048 + row) * 64 + ce)
                        : (Wt + (size_t)(h * 2048 + row) * 64 + (ce - 64));
    kdst[i] = i * 4096 + wid * 1024;
  }
  // V staging: 64 d-rows x 128B (64 kv) = 8KB -> 2 sweeps
  const f16* vsrc[2]; int vdst[2];
  #pragma unroll
  for (int i = 0; i < 2; ++i) {
    int p = i * 4096 + tid * 16;
    int row = p >> 7;                        // 0..63
    int col = (p & 127) ^ ((row & 7) << 4);
    vsrc[i] = Vt + (size_t)(bh * 64 + row) * 2048 + (col >> 1);
    vdst[i] = i * 4096 + wid * 1024;
  }

  int qrow = qt * 128 + wid * 32 + l31;
  int ktmax = 2 * qt + 1;

  // Q' fragments: k = ks*16 + hi*8 + [0..8); ks 0-3 from Q, 4-7 from U
  f16x8 qf[8];
  {
    const f16* qp = Q + (size_t)(bh * 2048 + qrow) * 64 + hi * 8;
    const f16* up = U + (size_t)qrow * 64 + hi * 8;
    #pragma unroll
    for (int ks = 0; ks < 4; ++ks) {
      qf[ks]     = *(const f16x8*)(qp + ks * 16);
      qf[4 + ks] = *(const f16x8*)(up + ks * 16);
    }
  }

  float m_i = -1e30f, l_i = 0.0f;
  f32x16 accA = {}, accB = {};

  // prologue: stage tile 0 into buf 0
  #pragma unroll
  for (int i = 0; i < 4; ++i) gload16(ksrc[i], sm + kdst[i]);
  #pragma unroll
  for (int i = 0; i < 2; ++i) gload16(vsrc[i], sm + 32768 + vdst[i]);
  __syncthreads();

  for (int kt = 0; kt <= ktmax; ++kt) {
    int cur = kt & 1;
    char* Ks = sm + cur * 16384;
    char* Vs = sm + 32768 + cur * 8192;

    if (kt < ktmax) {
      char* kb = sm + (cur ^ 1) * 16384;
      char* vb = sm + 32768 + (cur ^ 1) * 8192;
      #pragma unroll
      for (int i = 0; i < 4; ++i) gload16(ksrc[i] + (size_t)(kt + 1) * 4096, kb + kdst[i]);
      #pragma unroll
      for (int i = 0; i < 2; ++i) gload16(vsrc[i] + (size_t)(kt + 1) * 64, vb + vdst[i]);
    }

    // S^T = K' @ Q'^T : st0 = kv[0,32), st1 = kv[32,64)
    f32x16 st0 = {}, st1 = {};
    __builtin_amdgcn_s_setprio(1);
    #pragma unroll
    for (int ks = 0; ks < 8; ++ks) {
      int co = (ks * 32 + hi * 16) ^ swzK;
      f16x8 k0 = *(const f16x8*)(Ks + l31 * 256 + co);
      f16x8 k1 = *(const f16x8*)(Ks + (32 + l31) * 256 + co);
      st0 = __builtin_amdgcn_mfma_f32_32x32x16_f16(k0, qf[ks], st0, 0, 0, 0);
      st1 = __builtin_amdgcn_mfma_f32_32x32x16_f16(k1, qf[ks], st1, 0, 0, 0);
    }
    __builtin_amdgcn_s_setprio(0);

    int kv0 = kt * 64;
    if (kv0 + 63 > qt * 128 + wid * 32) {   // wave-uniform branch
      #pragma unroll
      for (int r = 0; r < 16; ++r) {
        int kvl = kv0 + (r & 3) + 8 * (r >> 2) + 4 * hi;
        if (kvl > qrow) st0[r] = -1e30f;
        if (kvl + 32 > qrow) st1[r] = -1e30f;
      }
    }

    // online softmax in exp2 space, defer-max (THR = 8)
    float pm = fmaxf(st0[0], st1[0]);
    #pragma unroll
    for (int r = 1; r < 16; ++r) pm = max3f(pm, st0[r], st1[r]);
    pm = fmaxf(pm, __shfl_xor(pm, 32, 64));
    if (!__all(pm <= m_i + 8.0f)) {
      float mnew = fmaxf(m_i, pm);
      float sc = __builtin_amdgcn_exp2f(m_i - mnew);
      l_i *= sc;
      accA *= sc;
      accB *= sc;
      m_i = mnew;
    }

    float ps = 0.0f;
    u32 pk0[8], pk1[8];
    #pragma unroll
    for (int j = 0; j < 8; ++j) {
      float a0 = __builtin_amdgcn_exp2f(st0[2 * j] - m_i);
      float a1 = __builtin_amdgcn_exp2f(st0[2 * j + 1] - m_i);
      float b0 = __builtin_amdgcn_exp2f(st1[2 * j] - m_i);
      float b1 = __builtin_amdgcn_exp2f(st1[2 * j + 1] - m_i);
      ps += (a0 + a1) + (b0 + b1);
      pk0[j] = pkrtz(a0, a1);
      pk1[j] = pkrtz(b0, b1);
    }
    ps += __shfl_xor(ps, 32, 64);
    l_i += ps;

    // redistribute P into PV B-fragments
    pl32swap(pk0[0], pk0[2]); pl32swap(pk0[1], pk0[3]);
    pl32swap(pk0[4], pk0[6]); pl32swap(pk0[5], pk0[7]);
    pl32swap(pk1[0], pk1[2]); pl32swap(pk1[1], pk1[3]);
    pl32swap(pk1[4], pk1[6]); pl32swap(pk1[5], pk1[7]);

    // PV: O^T += V^T @ P^T (4 kb-steps over 64 kv)
    __builtin_amdgcn_s_setprio(1);
    #pragma unroll
    for (int kb = 0; kb < 4; ++kb) {
      union { u32 w[4]; f16x8 v; } bf;
      const u32* pk = (kb < 2) ? pk0 : pk1;
      int base = (kb & 1) * 4;
      bf.w[0] = pk[base + 0]; bf.w[1] = pk[base + 1];
      bf.w[2] = pk[base + 2]; bf.w[3] = pk[base + 3];
      int co = (kb * 32 + hi * 16) ^ swzV;
      f16x8 v0 = *(const f16x8*)(Vs + l31 * 128 + co);
      f16x8 v1 = *(const f16x8*)(Vs + (32 + l31) * 128 + co);
      accA = __builtin_amdgcn_mfma_f32_32x32x16_f16(v0, bf.v, accA, 0, 0, 0);
      accB = __builtin_amdgcn_mfma_f32_32x32x16_f16(v1, bf.v, accB, 0, 0, 0);
    }
    __builtin_amdgcn_s_setprio(0);
    __syncthreads();
  }

  // epilogue: O[q][d] = acc^T / l
  float inv = __builtin_amdgcn_rcpf(l_i);
  f16* aop = AO + (size_t)(b * 2048 + qrow) * 1024 + h * 64;
  #pragma unroll
  for (int u = 0; u < 4; ++u) {
    uint2 ov;
    ov.x = pkrtz(accA[4 * u] * inv, accA[4 * u + 1] * inv);
    ov.y = pkrtz(accA[4 * u + 2] * inv, accA[4 * u + 3] * inv);
    *(uint2*)(aop + 8 * u + 4 * hi) = ov;
    ov.x = pkrtz(accB[4 * u] * inv, accB[4 * u + 1] * inv);
    ov.y = pkrtz(accB[4 * u + 2] * inv, accB[4 * u + 3] * inv);
    *(uint2*)(aop + 32 + 8 * u + 4 * hi) = ov;
  }
}

// ---------------- launcher ----------------

extern "C" void kernel_launch(void* const* d_in, const int* in_sizes, int n_in,
                              void* d_out, int out_size, void* d_ws, size_t ws_size,
                              hipStream_t stream) {
  const float* x     = (const float*)d_in[0];
  const float* Wqkv  = (const float*)d_in[1];
  const float* Wout  = (const float*)d_in[2];
  const float* alpha = (const float*)d_in[3];
  const float* beta  = (const float*)d_in[4];

  char* ws = (char*)d_ws;
  f16* Xh    = (f16*)(ws);                  // 16 MiB  (later reused as AO)
  f16* Wqkvh = (f16*)(ws + 16777216);       // 6 MiB
  f16* Wouth = (f16*)(ws + 23068672);       // 2 MiB
  f16* Qh    = (f16*)(ws + 25165824);       // 16 MiB
  f16* Kh    = (f16*)(ws + 41943040);       // 16 MiB
  f16* Vt    = (f16*)(ws + 58720256);       // 16 MiB
  f16* U     = (f16*)(ws + 75497472);       // 256 KiB
  f16* Wt    = (f16*)(ws + 75759616);       // 4 MiB
  f16* AO    = Xh;

  cvt_f32_f16<<<4096, 256, 0, stream>>>(x, Xh, 8388608);
  cvt_f32_f16<<<1536, 256, 0, stream>>>(Wqkv, Wqkvh, 3145728);
  cvt_f32_f16<<<512, 256, 0, stream>>>(Wout, Wouth, 1048576);
  build_tables<<<256, 256, 0, stream>>>(alpha, beta, U, Wt);
  gemm_qkv<<<768, 512, 0, stream>>>(Xh, Wqkvh, Qh, Kh, Vt);
  attn<<<1024, 256, 0, stream>>>(Qh, Kh, Vt, U, Wt, AO);
  gemm_out<<<256, 512, 0, stream>>>(AO, Wouth, (float*)d_out);
}

// Round 20
// 157.168 us; speedup vs baseline: 1.1693x; 1.0365x over previous
//
#include <hip/hip_runtime.h>
#include <cstdint>
#include <cstddef>

typedef _Float16 f16;
typedef f16 f16x8 __attribute__((ext_vector_type(8)));
typedef __fp16 fp16x2 __attribute__((ext_vector_type(2)));
typedef float f32x4 __attribute__((ext_vector_type(4)));
typedef float f32x16 __attribute__((ext_vector_type(16)));
typedef uint32_t u32;

// ---------------- helpers ----------------

__device__ __forceinline__ void gload16(const void* g, void* l) {
  __builtin_amdgcn_global_load_lds((const __attribute__((address_space(1))) void*)g,
                                   (__attribute__((address_space(3))) void*)l,
                                   16u, 0, 0u);
}

__device__ __forceinline__ u32 pkrtz(float a, float b) {
  union { fp16x2 v; u32 u; } t;
  t.v = __builtin_amdgcn_cvt_pkrtz(a, b);
  return t.u;
}

__device__ __forceinline__ u32 packh2(float a, float b) { return pkrtz(a, b); }

__device__ __forceinline__ float max3f(float a, float b, float c) {
  return fmaxf(fmaxf(a, b), c);
}

// exchange halves between a and b (used ONLY with distance>=8 from writes of
// its inputs -- VALU->permlane hazard; see R7 post-mortem)
__device__ __forceinline__ void pl32swap(u32& a, u32& b) {
  asm volatile("v_permlane32_swap_b32 %0, %1" : "+v"(a), "+v"(b));
}

// ---------------- fused prep: 3x fp32->fp16 cvt + bias tables ----------------
// Segmented grid: [0,4096) x->Xh, [4096,5632) Wqkv, [5632,6144) Wout,
// [6144,6400) build U/Wt tables. Saves 3 kernel-launch gaps + lets the small
// segments overlap the big one.

__device__ __forceinline__ void cvt8(const float* __restrict__ in,
                                     f16* __restrict__ out, int i) {
  float4 a = *(const float4*)(in + i);
  float4 b = *(const float4*)(in + i + 4);
  f16x8 o;
  o[0] = (f16)a.x; o[1] = (f16)a.y; o[2] = (f16)a.z; o[3] = (f16)a.w;
  o[4] = (f16)b.x; o[5] = (f16)b.y; o[6] = (f16)b.z; o[7] = (f16)b.w;
  *(f16x8*)(out + i) = o;
}

__global__ __launch_bounds__(256) void prep(const float* __restrict__ x,
                                            const float* __restrict__ Wqkv,
                                            const float* __restrict__ Wout,
                                            const float* __restrict__ alpha,
                                            const float* __restrict__ beta,
                                            f16* __restrict__ Xh,
                                            f16* __restrict__ Wqkvh,
                                            f16* __restrict__ Wouth,
                                            f16* __restrict__ U,
                                            f16* __restrict__ Wt) {
  int blk = blockIdx.x;
  int tid = threadIdx.x;
  if (blk < 4096) {
    cvt8(x, Xh, (blk * 256 + tid) * 8);
  } else if (blk < 5632) {
    cvt8(Wqkv, Wqkvh, ((blk - 4096) * 256 + tid) * 8);
  } else if (blk < 6144) {
    cvt8(Wout, Wouth, ((blk - 5632) * 256 + tid) * 8);
  } else {
    int idx = (blk - 6144) * 256 + tid;     // t*32 + r
    int t = idx >> 5, r = idx & 31;
    float w = powf(10000.0f, -(float)r / 32.0f);
    float ang = w * (float)t;
    float c = cosf(ang), s = sinf(ang);
    const float L2E = 1.44269504089f;
    U[t * 64 + 2 * r]     = (f16)(c * L2E);
    U[t * 64 + 2 * r + 1] = (f16)(s * L2E);
    #pragma unroll
    for (int h = 0; h < 16; ++h) {
      float al = alpha[h * 32 + r], be = beta[h * 32 + r];
      Wt[(size_t)(h * 2048 + t) * 64 + 2 * r]     = (f16)(al * c - be * s);
      Wt[(size_t)(h * 2048 + t) * 64 + 2 * r + 1] = (f16)(al * s + be * c);
    }
  }
}

// ---------------- GEMM core (BM=256, BN=128, BK=64, 8 waves) ----------
// m-major-per-XCD partition (R14, proven).

__global__ __launch_bounds__(512, 2) void gemm_qkv(const f16* __restrict__ A,
                                                   const f16* __restrict__ B,
                                                   f16* __restrict__ Q,
                                                   f16* __restrict__ Kh,
                                                   f16* __restrict__ Vt) {
  __shared__ __align__(16) char sm[147456];
  const int K = 1024;
  int tid = threadIdx.x;
  int lane = tid & 63, wid = tid >> 6;
  int bid = blockIdx.x;
  int xcd = bid & 7;
  int id = bid >> 3;
  int ml = id / 24;
  int nn = id % 24;
  int m0 = (xcd * 4 + ml) * 256;
  int n0 = nn * 128;
  int wm = wid >> 1, wn = wid & 1;
  int c = lane & 15, g = lane >> 4;
  int swz = (c & 7) << 4;

  const f16* asrc[4]; int adst[4];
  #pragma unroll
  for (int i = 0; i < 4; ++i) {
    int p = i * 8192 + tid * 16;
    int row = p >> 7;
    int col = (p & 127) ^ ((row & 7) << 4);
    asrc[i] = A + (size_t)(m0 + row) * K + (col >> 1);
    adst[i] = i * 8192 + wid * 1024;
  }
  const f16* bsrc[2]; int bdst[2];
  #pragma unroll
  for (int i = 0; i < 2; ++i) {
    int p = i * 8192 + tid * 16;
    int row = p >> 7;
    int col = (p & 127) ^ ((row & 7) << 4);
    bsrc[i] = B + (size_t)(n0 + row) * K + (col >> 1);
    bdst[i] = i * 8192 + wid * 1024;
  }

  f32x4 acc[4][4] = {};

  #pragma unroll
  for (int i = 0; i < 4; ++i) gload16(asrc[i], sm + adst[i]);
  #pragma unroll
  for (int i = 0; i < 2; ++i) gload16(bsrc[i], sm + 98304 + bdst[i]);
  #pragma unroll
  for (int i = 0; i < 4; ++i) gload16(asrc[i] + 64, sm + 32768 + adst[i]);
  #pragma unroll
  for (int i = 0; i < 2; ++i) gload16(bsrc[i] + 64, sm + 98304 + 16384 + bdst[i]);

  for (int kt = 0; kt < 16; ++kt) {
    if (kt < 15) asm volatile("s_waitcnt vmcnt(6)" ::: "memory");
    else         asm volatile("s_waitcnt vmcnt(0)" ::: "memory");
    __builtin_amdgcn_s_barrier();

    int j = kt % 3;
    char* As = sm + j * 32768;
    char* Bs = sm + 98304 + j * 16384;
    int jn = (kt + 2) % 3;
    char* Ad = sm + jn * 32768;
    char* Bd = sm + 98304 + jn * 16384;
    bool stg = (kt <= 13);

    if (stg) {
      gload16(asrc[0] + (kt + 2) * 64, Ad + adst[0]);
      gload16(asrc[1] + (kt + 2) * 64, Ad + adst[1]);
      gload16(asrc[2] + (kt + 2) * 64, Ad + adst[2]);
    }
    {
      int co = (g * 16) ^ swz;
      f16x8 af[4], bf[4];
      #pragma unroll
      for (int fr = 0; fr < 4; ++fr)
        af[fr] = *(const f16x8*)(As + (wm * 64 + fr * 16 + c) * 128 + co);
      #pragma unroll
      for (int fn = 0; fn < 4; ++fn)
        bf[fn] = *(const f16x8*)(Bs + (wn * 64 + fn * 16 + c) * 128 + co);
      __builtin_amdgcn_s_setprio(1);
      #pragma unroll
      for (int fr = 0; fr < 4; ++fr)
        #pragma unroll
        for (int fn = 0; fn < 4; ++fn)
          acc[fr][fn] = __builtin_amdgcn_mfma_f32_16x16x32_f16(af[fr], bf[fn], acc[fr][fn], 0, 0, 0);
      __builtin_amdgcn_s_setprio(0);
    }
    if (stg) {
      gload16(asrc[3] + (kt + 2) * 64, Ad + adst[3]);
      gload16(bsrc[0] + (kt + 2) * 64, Bd + bdst[0]);
      gload16(bsrc[1] + (kt + 2) * 64, Bd + bdst[1]);
    }
    {
      int co = (64 + g * 16) ^ swz;
      f16x8 af[4], bf[4];
      #pragma unroll
      for (int fr = 0; fr < 4; ++fr)
        af[fr] = *(const f16x8*)(As + (wm * 64 + fr * 16 + c) * 128 + co);
      #pragma unroll
      for (int fn = 0; fn < 4; ++fn)
        bf[fn] = *(const f16x8*)(Bs + (wn * 64 + fn * 16 + c) * 128 + co);
      __builtin_amdgcn_s_setprio(1);
      #pragma unroll
      for (int fr = 0; fr < 4; ++fr)
        #pragma unroll
        for (int fn = 0; fn < 4; ++fn)
          acc[fr][fn] = __builtin_amdgcn_mfma_f32_16x16x32_f16(af[fr], bf[fn], acc[fr][fn], 0, 0, 0);
      __builtin_amdgcn_s_setprio(0);
    }
  }

  int which = n0 >> 10;
  #pragma unroll
  for (int fr = 0; fr < 4; ++fr) {
    int m = m0 + wm * 64 + fr * 16 + g * 4;
    int b = m >> 11, t = m & 2047;
    #pragma unroll
    for (int fn = 0; fn < 4; ++fn) {
      int n = n0 + wn * 64 + fn * 16 + c;
      int nf = n & 1023, hh = nf >> 6, d = nf & 63;
      if (which == 0) {
        #pragma unroll
        for (int r = 0; r < 4; ++r)
          Q[(size_t)((b * 16 + hh) * 2048 + (t + r)) * 64 + d] = (f16)(acc[fr][fn][r] * 0.180336880111f);
      } else if (which == 1) {
        #pragma unroll
        for (int r = 0; r < 4; ++r)
          Kh[(size_t)((b * 16 + hh) * 2048 + (t + r)) * 64 + d] = (f16)acc[fr][fn][r];
      } else {
        uint2 pk;
        pk.x = packh2(acc[fr][fn][0], acc[fr][fn][1]);
        pk.y = packh2(acc[fr][fn][2], acc[fr][fn][3]);
        *(uint2*)(Vt + (size_t)((b * 16 + hh) * 64 + d) * 2048 + t) = pk;
      }
    }
  }
}

// ---------------- GEMM2: out = AO @ Wout^T (fp32 out) ----------------

__global__ __launch_bounds__(512, 2) void gemm_out(const f16* __restrict__ A,
                                                   const f16* __restrict__ B,
                                                   float* __restrict__ Cout) {
  __shared__ __align__(16) char sm[147456];
  const int K = 1024;
  int tid = threadIdx.x;
  int lane = tid & 63, wid = tid >> 6;
  int bid = blockIdx.x;
  int xcd = bid & 7;
  int id = bid >> 3;
  int m0 = (xcd * 4 + id / 8) * 256;
  int n0 = (id & 7) * 128;
  int wm = wid >> 1, wn = wid & 1;
  int c = lane & 15, g = lane >> 4;
  int swz = (c & 7) << 4;

  const f16* asrc[4]; int adst[4];
  #pragma unroll
  for (int i = 0; i < 4; ++i) {
    int p = i * 8192 + tid * 16;
    int row = p >> 7;
    int col = (p & 127) ^ ((row & 7) << 4);
    asrc[i] = A + (size_t)(m0 + row) * K + (col >> 1);
    adst[i] = i * 8192 + wid * 1024;
  }
  const f16* bsrc[2]; int bdst[2];
  #pragma unroll
  for (int i = 0; i < 2; ++i) {
    int p = i * 8192 + tid * 16;
    int row = p >> 7;
    int col = (p & 127) ^ ((row & 7) << 4);
    bsrc[i] = B + (size_t)(n0 + row) * K + (col >> 1);
    bdst[i] = i * 8192 + wid * 1024;
  }

  f32x4 acc[4][4] = {};

  #pragma unroll
  for (int i = 0; i < 4; ++i) gload16(asrc[i], sm + adst[i]);
  #pragma unroll
  for (int i = 0; i < 2; ++i) gload16(bsrc[i], sm + 98304 + bdst[i]);
  #pragma unroll
  for (int i = 0; i < 4; ++i) gload16(asrc[i] + 64, sm + 32768 + adst[i]);
  #pragma unroll
  for (int i = 0; i < 2; ++i) gload16(bsrc[i] + 64, sm + 98304 + 16384 + bdst[i]);

  for (int kt = 0; kt < 16; ++kt) {
    if (kt < 15) asm volatile("s_waitcnt vmcnt(6)" ::: "memory");
    else         asm volatile("s_waitcnt vmcnt(0)" ::: "memory");
    __builtin_amdgcn_s_barrier();

    int j = kt % 3;
    char* As = sm + j * 32768;
    char* Bs = sm + 98304 + j * 16384;
    int jn = (kt + 2) % 3;
    char* Ad = sm + jn * 32768;
    char* Bd = sm + 98304 + jn * 16384;
    bool stg = (kt <= 13);

    if (stg) {
      gload16(asrc[0] + (kt + 2) * 64, Ad + adst[0]);
      gload16(asrc[1] + (kt + 2) * 64, Ad + adst[1]);
      gload16(asrc[2] + (kt + 2) * 64, Ad + adst[2]);
    }
    {
      int co = (g * 16) ^ swz;
      f16x8 af[4], bf[4];
      #pragma unroll
      for (int fr = 0; fr < 4; ++fr)
        af[fr] = *(const f16x8*)(As + (wm * 64 + fr * 16 + c) * 128 + co);
      #pragma unroll
      for (int fn = 0; fn < 4; ++fn)
        bf[fn] = *(const f16x8*)(Bs + (wn * 64 + fn * 16 + c) * 128 + co);
      __builtin_amdgcn_s_setprio(1);
      #pragma unroll
      for (int fr = 0; fr < 4; ++fr)
        #pragma unroll
        for (int fn = 0; fn < 4; ++fn)
          acc[fr][fn] = __builtin_amdgcn_mfma_f32_16x16x32_f16(af[fr], bf[fn], acc[fr][fn], 0, 0, 0);
      __builtin_amdgcn_s_setprio(0);
    }
    if (stg) {
      gload16(asrc[3] + (kt + 2) * 64, Ad + adst[3]);
      gload16(bsrc[0] + (kt + 2) * 64, Bd + bdst[0]);
      gload16(bsrc[1] + (kt + 2) * 64, Bd + bdst[1]);
    }
    {
      int co = (64 + g * 16) ^ swz;
      f16x8 af[4], bf[4];
      #pragma unroll
      for (int fr = 0; fr < 4; ++fr)
        af[fr] = *(const f16x8*)(As + (wm * 64 + fr * 16 + c) * 128 + co);
      #pragma unroll
      for (int fn = 0; fn < 4; ++fn)
        bf[fn] = *(const f16x8*)(Bs + (wn * 64 + fn * 16 + c) * 128 + co);
      __builtin_amdgcn_s_setprio(1);
      #pragma unroll
      for (int fr = 0; fr < 4; ++fr)
        #pragma unroll
        for (int fn = 0; fn < 4; ++fn)
          acc[fr][fn] = __builtin_amdgcn_mfma_f32_16x16x32_f16(af[fr], bf[fn], acc[fr][fn], 0, 0, 0);
      __builtin_amdgcn_s_setprio(0);
    }
  }

  #pragma unroll
  for (int fr = 0; fr < 4; ++fr) {
    int m = m0 + wm * 64 + fr * 16 + g * 4;
    #pragma unroll
    for (int fn = 0; fn < 4; ++fn) {
      int n = n0 + wn * 64 + fn * 16 + c;
      #pragma unroll
      for (int r = 0; r < 4; ++r)
        Cout[(size_t)(m + r) * 1024 + n] = acc[fr][fn][r];
    }
  }
}

// ---------------- flash attention (4 waves, q-tile 128, KVBLK 64) ----------
// __launch_bounds__(256, 3): 3 waves/SIMD (proven 76.5 us; 4 waves spills --
// R18). 48KB LDS x 3 blocks = 144KB. Grid 1024, big tiles first, o&63=bh
// keeps XCD pinning. Internals = proven R8/R16 attn.

__global__ __launch_bounds__(256, 3) void attn(const f16* __restrict__ Q,
                                               const f16* __restrict__ Kh,
                                               const f16* __restrict__ Vt,
                                               const f16* __restrict__ U,
                                               const f16* __restrict__ Wt,
                                               f16* __restrict__ AO) {
  __shared__ __align__(16) char sm[49152];   // K' 2x16K | V 2x8K
  int tid = threadIdx.x, lane = tid & 63, wid = tid >> 6;   // 4 waves
  int l31 = lane & 31, hi = lane >> 5;
  int o = blockIdx.x;
  int qt = 15 - (o >> 6);          // big tiles first
  int bh = o & 63;
  int h = bh & 15, b = bh >> 4;
  int swzK = (lane & 15) << 4;     // K' rows 256B
  int swzV = (lane & 7) << 4;      // V rows 128B

  // K' staging: 64 rows x 256B = 16KB -> 4 sweeps of 4KB
  const f16* ksrc[4]; int kdst[4];
  #pragma unroll
  for (int i = 0; i < 4; ++i) {
    int p = i * 4096 + tid * 16;
    int row = p >> 8;                        // 0..63
    int col = (p & 255) ^ ((row & 15) << 4);
    int ce = col >> 1;
    ksrc[i] = (ce < 64) ? (Kh + (size_t)(bh * 2048 + row) * 64 + ce)
                        : (Wt + (size_t)(h * 2048 + row) * 64 + (ce - 64));
    kdst[i] = i * 4096 + wid * 1024;
  }
  // V staging: 64 d-rows x 128B (64 kv) = 8KB -> 2 sweeps
  const f16* vsrc[2]; int vdst[2];
  #pragma unroll
  for (int i = 0; i < 2; ++i) {
    int p = i * 4096 + tid * 16;
    int row = p >> 7;                        // 0..63
    int col = (p & 127) ^ ((row & 7) << 4);
    vsrc[i] = Vt + (size_t)(bh * 64 + row) * 2048 + (col >> 1);
    vdst[i] = i * 4096 + wid * 1024;
  }

  int qrow = qt * 128 + wid * 32 + l31;
  int ktmax = 2 * qt + 1;

  // Q' fragments: k = ks*16 + hi*8 + [0..8); ks 0-3 from Q, 4-7 from U
  f16x8 qf[8];
  {
    const f16* qp = Q + (size_t)(bh * 2048 + qrow) * 64 + hi * 8;
    const f16* up = U + (size_t)qrow * 64 + hi * 8;
    #pragma unroll
    for (int ks = 0; ks < 4; ++ks) {
      qf[ks]     = *(const f16x8*)(qp + ks * 16);
      qf[4 + ks] = *(const f16x8*)(up + ks * 16);
    }
  }

  float m_i = -1e30f, l_i = 0.0f;
  f32x16 accA = {}, accB = {};

  // prologue: stage tile 0 into buf 0
  #pragma unroll
  for (int i = 0; i < 4; ++i) gload16(ksrc[i], sm + kdst[i]);
  #pragma unroll
  for (int i = 0; i < 2; ++i) gload16(vsrc[i], sm + 32768 + vdst[i]);
  __syncthreads();

  for (int kt = 0; kt <= ktmax; ++kt) {
    int cur = kt & 1;
    char* Ks = sm + cur * 16384;
    char* Vs = sm + 32768 + cur * 8192;

    if (kt < ktmax) {
      char* kb = sm + (cur ^ 1) * 16384;
      char* vb = sm + 32768 + (cur ^ 1) * 8192;
      #pragma unroll
      for (int i = 0; i < 4; ++i) gload16(ksrc[i] + (size_t)(kt + 1) * 4096, kb + kdst[i]);
      #pragma unroll
      for (int i = 0; i < 2; ++i) gload16(vsrc[i] + (size_t)(kt + 1) * 64, vb + vdst[i]);
    }

    // S^T = K' @ Q'^T : st0 = kv[0,32), st1 = kv[32,64)
    f32x16 st0 = {}, st1 = {};
    __builtin_amdgcn_s_setprio(1);
    #pragma unroll
    for (int ks = 0; ks < 8; ++ks) {
      int co = (ks * 32 + hi * 16) ^ swzK;
      f16x8 k0 = *(const f16x8*)(Ks + l31 * 256 + co);
      f16x8 k1 = *(const f16x8*)(Ks + (32 + l31) * 256 + co);
      st0 = __builtin_amdgcn_mfma_f32_32x32x16_f16(k0, qf[ks], st0, 0, 0, 0);
      st1 = __builtin_amdgcn_mfma_f32_32x32x16_f16(k1, qf[ks], st1, 0, 0, 0);
    }
    __builtin_amdgcn_s_setprio(0);

    int kv0 = kt * 64;
    if (kv0 + 63 > qt * 128 + wid * 32) {   // wave-uniform branch
      #pragma unroll
      for (int r = 0; r < 16; ++r) {
        int kvl = kv0 + (r & 3) + 8 * (r >> 2) + 4 * hi;
        if (kvl > qrow) st0[r] = -1e30f;
        if (kvl + 32 > qrow) st1[r] = -1e30f;
      }
    }

    // online softmax in exp2 space, defer-max (THR = 8)
    float pm = fmaxf(st0[0], st1[0]);
    #pragma unroll
    for (int r = 1; r < 16; ++r) pm = max3f(pm, st0[r], st1[r]);
    pm = fmaxf(pm, __shfl_xor(pm, 32, 64));
    if (!__all(pm <= m_i + 8.0f)) {
      float mnew = fmaxf(m_i, pm);
      float sc = __builtin_amdgcn_exp2f(m_i - mnew);
      l_i *= sc;
      accA *= sc;
      accB *= sc;
      m_i = mnew;
    }

    float ps = 0.0f;
    u32 pk0[8], pk1[8];
    #pragma unroll
    for (int j = 0; j < 8; ++j) {
      float a0 = __builtin_amdgcn_exp2f(st0[2 * j] - m_i);
      float a1 = __builtin_amdgcn_exp2f(st0[2 * j + 1] - m_i);
      float b0 = __builtin_amdgcn_exp2f(st1[2 * j] - m_i);
      float b1 = __builtin_amdgcn_exp2f(st1[2 * j + 1] - m_i);
      ps += (a0 + a1) + (b0 + b1);
      pk0[j] = pkrtz(a0, a1);
      pk1[j] = pkrtz(b0, b1);
    }
    ps += __shfl_xor(ps, 32, 64);
    l_i += ps;

    // redistribute P into PV B-fragments
    pl32swap(pk0[0], pk0[2]); pl32swap(pk0[1], pk0[3]);
    pl32swap(pk0[4], pk0[6]); pl32swap(pk0[5], pk0[7]);
    pl32swap(pk1[0], pk1[2]); pl32swap(pk1[1], pk1[3]);
    pl32swap(pk1[4], pk1[6]); pl32swap(pk1[5], pk1[7]);

    // PV: O^T += V^T @ P^T (4 kb-steps over 64 kv)
    __builtin_amdgcn_s_setprio(1);
    #pragma unroll
    for (int kb = 0; kb < 4; ++kb) {
      union { u32 w[4]; f16x8 v; } bf;
      const u32* pk = (kb < 2) ? pk0 : pk1;
      int base = (kb & 1) * 4;
      bf.w[0] = pk[base + 0]; bf.w[1] = pk[base + 1];
      bf.w[2] = pk[base + 2]; bf.w[3] = pk[base + 3];
      int co = (kb * 32 + hi * 16) ^ swzV;
      f16x8 v0 = *(const f16x8*)(Vs + l31 * 128 + co);
      f16x8 v1 = *(const f16x8*)(Vs + (32 + l31) * 128 + co);
      accA = __builtin_amdgcn_mfma_f32_32x32x16_f16(v0, bf.v, accA, 0, 0, 0);
      accB = __builtin_amdgcn_mfma_f32_32x32x16_f16(v1, bf.v, accB, 0, 0, 0);
    }
    __builtin_amdgcn_s_setprio(0);
    __syncthreads();
  }

  // epilogue: O[q][d] = acc^T / l
  float inv = __builtin_amdgcn_rcpf(l_i);
  f16* aop = AO + (size_t)(b * 2048 + qrow) * 1024 + h * 64;
  #pragma unroll
  for (int u = 0; u < 4; ++u) {
    uint2 ov;
    ov.x = pkrtz(accA[4 * u] * inv, accA[4 * u + 1] * inv);
    ov.y = pkrtz(accA[4 * u + 2] * inv, accA[4 * u + 3] * inv);
    *(uint2*)(aop + 8 * u + 4 * hi) = ov;
    ov.x = pkrtz(accB[4 * u] * inv, accB[4 * u + 1] * inv);
    ov.y = pkrtz(accB[4 * u + 2] * inv, accB[4 * u + 3] * inv);
    *(uint2*)(aop + 32 + 8 * u + 4 * hi) = ov;
  }
}

// ---------------- launcher ----------------

extern "C" void kernel_launch(void* const* d_in, const int* in_sizes, int n_in,
                              void* d_out, int out_size, void* d_ws, size_t ws_size,
                              hipStream_t stream) {
  const float* x     = (const float*)d_in[0];
  const float* Wqkv  = (const float*)d_in[1];
  const float* Wout  = (const float*)d_in[2];
  const float* alpha = (const float*)d_in[3];
  const float* beta  = (const float*)d_in[4];

  char* ws = (char*)d_ws;
  f16* Xh    = (f16*)(ws);                  // 16 MiB  (later reused as AO)
  f16* Wqkvh = (f16*)(ws + 16777216);       // 6 MiB
  f16* Wouth = (f16*)(ws + 23068672);       // 2 MiB
  f16* Qh    = (f16*)(ws + 25165824);       // 16 MiB
  f16* Kh    = (f16*)(ws + 41943040);       // 16 MiB
  f16* Vt    = (f16*)(ws + 58720256);       // 16 MiB
  f16* U     = (f16*)(ws + 75497472);       // 256 KiB
  f16* Wt    = (f16*)(ws + 75759616);       // 4 MiB
  f16* AO    = Xh;

  prep<<<6400, 256, 0, stream>>>(x, Wqkv, Wout, alpha, beta, Xh, Wqkvh, Wouth, U, Wt);
  gemm_qkv<<<768, 512, 0, stream>>>(Xh, Wqkvh, Qh, Kh, Vt);
  attn<<<1024, 256, 0, stream>>>(Qh, Kh, Vt, U, Wt, AO);
  gemm_out<<<256, 512, 0, stream>>>(AO, Wouth, (float*)d_out);
}